// Round 2
// baseline (7416.415 us; speedup 1.0000x reference)
//
#include <hip/hip_runtime.h>
#include <math.h>

// ---------------------------------------------------------------------------
// DelayRNN: persistent-kernel fp32 implementation.
// R2: switch gumbel bits to jax's threefry_partitionable path
//     (bits[i] = o0^o1 of threefry2x32(key, (hi32(i), lo32(i)))) — default
//     since jax 0.4.36. Original split-counter path gave absmax 7.8e-2
//     (every gate selection wrong). Everything else unchanged from R1.
// ---------------------------------------------------------------------------

#define kB 32
#define kT 128
#define kI 64
#define kH 256
#define kD 32
#define kC 64
#define kOut 32
#define kSteps (kT + kOut)            // 160
#define NB 64
#define NTHR 256
#define NT_ALL (NB * NTHR)            // 16384
#define NB_M (NB - 1)

// ws layout, float offsets (all 16B-aligned)
#define WS_H    64
#define WS_MEM  (WS_H + kB*kH)                  // h: [B][H]
#define WS_A    (WS_MEM + kB*kSteps*kI)         // mem events: [B][160][I]
#define WS_GH   (WS_A + kB*kH)                  // a (elu(e1)): [B][H]
#define WS_L1   (WS_GH + kB*3*kH)               // gh: [B][3H]
#define WS_O1   (WS_L1 + kB*kD)                 // l1 (elu(dg1)): [B][D]
#define WS_W2   (WS_O1 + kB*kH)                 // o1 (relu(f1)): [B][H]
#define WS_B2   (WS_W2 + kH*3*kH)               // W_e2ih: [H][3H]
#define WS_G    (WS_B2 + 3*kH)                  // b_e2ih: [3H]
#define WS_TOTAL (WS_G + kT*kB*kD)              // g_enc: [T*B*D]
#define WS_ZERO_BYTES ((size_t)WS_A * sizeof(float))  // zero bar+h+mem

// ---- Threefry-2x32 (matches jax.random exactly) ----
__device__ __forceinline__ void tf2x32(unsigned k0, unsigned k1,
                                       unsigned x0, unsigned x1,
                                       unsigned& o0, unsigned& o1) {
  unsigned ks2 = k0 ^ k1 ^ 0x1BD11BDAu;
  unsigned v0 = x0 + k0, v1 = x1 + k1;
#define TFR(r) { v0 += v1; v1 = (v1 << (r)) | (v1 >> (32-(r))); v1 ^= v0; }
  TFR(13) TFR(15) TFR(26) TFR(6)   v0 += k1;  v1 += ks2 + 1u;
  TFR(17) TFR(29) TFR(16) TFR(24)  v0 += ks2; v1 += k0  + 2u;
  TFR(13) TFR(15) TFR(26) TFR(6)   v0 += k0;  v1 += k1  + 3u;
  TFR(17) TFR(29) TFR(16) TFR(24)  v0 += k1;  v1 += ks2 + 4u;
  TFR(13) TFR(15) TFR(26) TFR(6)   v0 += ks2; v1 += k0  + 5u;
#undef TFR
  o0 = v0; o1 = v1;
}

__device__ __forceinline__ float bits_to_gumbel(unsigned bits) {
  // jax _uniform: f = bitcast((bits>>9)|0x3F800000) - 1; u = f*(1-tiny)+tiny
  float f = __uint_as_float((bits >> 9) | 0x3F800000u) - 1.0f;
  float u = f + 1.17549435e-38f;
  return -logf(-logf(u));
}

// Monotonic-counter grid barrier; device-scope fences handle cross-XCD L2.
__device__ __forceinline__ void gridbar(unsigned* bar, unsigned target) {
  __syncthreads();
  if (threadIdx.x == 0) {
    __threadfence();   // make this block's stores visible device-wide
    __hip_atomic_fetch_add(bar, 1u, __ATOMIC_ACQ_REL, __HIP_MEMORY_SCOPE_AGENT);
    while (__hip_atomic_load(bar, __ATOMIC_RELAXED, __HIP_MEMORY_SCOPE_AGENT) < target)
      __builtin_amdgcn_s_sleep(1);
    __threadfence();   // acquire: invalidate stale cached lines
  }
  __syncthreads();
}

__global__ __launch_bounds__(NTHR)
void delay_rnn(const float* __restrict__ x, const int* __restrict__ lengths,
               const float* __restrict__ W_dg1, const float* __restrict__ b_dg1,
               const float* __restrict__ W_dg2, const float* __restrict__ b_dg2,
               const float* __restrict__ W_e1,  const float* __restrict__ b_e1,
               const float* __restrict__ W_e2,  const float* __restrict__ b_e2,
               const float* __restrict__ W_ih,  const float* __restrict__ b_ih,
               const float* __restrict__ W_hh,  const float* __restrict__ b_hh,
               const float* __restrict__ W_f1,  const float* __restrict__ b_f1,
               const float* __restrict__ W_f2,  const float* __restrict__ b_f2,
               float* __restrict__ out, float* __restrict__ ws) {
  const int tid = threadIdx.x;
  const int bid = blockIdx.x;
  const int gid = bid * NTHR + tid;

  unsigned* bar = (unsigned*)ws;
  float* h   = ws + WS_H;
  float* mem = ws + WS_MEM;
  float* av  = ws + WS_A;
  float* gh  = ws + WS_GH;
  float* l1  = ws + WS_L1;
  float* o1  = ws + WS_O1;
  float* W2  = ws + WS_W2;
  float* B2  = ws + WS_B2;
  float* g   = ws + WS_G;

  __shared__ float lg[kB][kD];
  __shared__ int   sel[kB];
  __shared__ float dec_s[kD];

  // ---------------- init phase ----------------
  {
    unsigned k0, k1;
    tf2x32(0u, 42u, 0u, 0u, k0, k1);           // fold_in(key(42), 0)
    const int n = kT * kB * kD;                // 131072
    for (int i = gid; i < n; i += NT_ALL) {
      // jax threefry_partitionable 32-bit bits: counters (hi32(i), lo32(i)),
      // output = o0 ^ o1
      unsigned a, b;
      tf2x32(k0, k1, 0u, (unsigned)i, a, b);
      g[i] = bits_to_gumbel(a ^ b);
    }
  }
  // W2 = W_e2 @ W_ih ; B2 = b_ih + b_e2 @ W_ih
  for (int idx = gid; idx < kH * 3 * kH; idx += NT_ALL) {
    int k = idx / (3 * kH), n = idx % (3 * kH);
    const float* wr = W_e2 + k * kH;
    float s0 = 0, s1 = 0, s2 = 0, s3 = 0;
    for (int m = 0; m < kH; m += 4) {
      float4 wv = *(const float4*)(wr + m);
      s0 += wv.x * W_ih[(m    ) * 3 * kH + n];
      s1 += wv.y * W_ih[(m + 1) * 3 * kH + n];
      s2 += wv.z * W_ih[(m + 2) * 3 * kH + n];
      s3 += wv.w * W_ih[(m + 3) * 3 * kH + n];
    }
    W2[idx] = ((s0 + s1) + (s2 + s3));
  }
  for (int n = gid; n < 3 * kH; n += NT_ALL) {
    float s = b_ih[n];
    for (int m = 0; m < kH; ++m) s += b_e2[m] * W_ih[m * 3 * kH + n];
    B2[n] = s;
  }

  unsigned round = 1;
  gridbar(bar, NB * round); round++;

  // ---------------- time loop: s = 0..160 (160 = output-head epilogue) -----
  for (int s = 0; s <= kSteps; ++s) {
    const bool enc  = (s < kT);
    const bool rnn  = (s < kSteps);
    const bool head = (s > kT);    // produce out row k = s-1-kT

    // ============ PHASE 1: dg1 | gh | e1 | f1 (flat list, all blocks) =====
    {
      const int nDG1 = enc  ? kB * kD     : 0;  // 1024
      const int nGH  = rnn  ? kB * 3 * kH : 0;  // 24576
      const int nE1  = rnn  ? kB * kH     : 0;  // 8192
      const int nF1  = head ? kB * kH     : 0;  // 8192
      const int ntask = nDG1 + nGH + nE1 + nF1;
      for (int i = gid; i < ntask; i += NT_ALL) {
        if (i < nDG1) {
          int b = i >> 5, j = i & 31;
          const float* xr = x + (b * kT + s) * kI;
          const float* hr = h + b * kH;
          float s0 = 0, s1 = 0, s2 = 0, s3 = 0;
          for (int k = 0; k < kI; k += 4) {
            float4 xv = *(const float4*)(xr + k);
            s0 += xv.x * W_dg1[(k    ) * kD + j];
            s1 += xv.y * W_dg1[(k + 1) * kD + j];
            s2 += xv.z * W_dg1[(k + 2) * kD + j];
            s3 += xv.w * W_dg1[(k + 3) * kD + j];
          }
          for (int k = 0; k < kH; k += 4) {
            float4 hv = *(const float4*)(hr + k);
            s0 += hv.x * W_dg1[(kI + k    ) * kD + j];
            s1 += hv.y * W_dg1[(kI + k + 1) * kD + j];
            s2 += hv.z * W_dg1[(kI + k + 2) * kD + j];
            s3 += hv.w * W_dg1[(kI + k + 3) * kD + j];
          }
          float v = ((s0 + s1) + (s2 + s3)) + b_dg1[j];
          l1[i] = v > 0.f ? v : expm1f(v);
        } else if (i < nDG1 + nGH) {
          int ii = i - nDG1;
          int b = ii / (3 * kH), j = ii % (3 * kH);
          const float* hr = h + b * kH;
          float s0 = 0, s1 = 0, s2 = 0, s3 = 0;
          for (int k = 0; k < kH; k += 4) {
            float4 hv = *(const float4*)(hr + k);
            s0 += hv.x * W_hh[(k    ) * 3 * kH + j];
            s1 += hv.y * W_hh[(k + 1) * 3 * kH + j];
            s2 += hv.z * W_hh[(k + 2) * 3 * kH + j];
            s3 += hv.w * W_hh[(k + 3) * 3 * kH + j];
          }
          gh[ii] = ((s0 + s1) + (s2 + s3)) + b_hh[j];
        } else if (i < nDG1 + nGH + nE1) {
          int ii = i - nDG1 - nGH;
          int b = ii / kH, j = ii % kH;
          float s0 = 0, s1 = 0, s2 = 0, s3 = 0;
          if (enc) {  // decoder uses x_zero: skip first 64 rows
            const float* xr = x + (b * kT + s) * kI;
            for (int k = 0; k < kI; k += 4) {
              float4 xv = *(const float4*)(xr + k);
              s0 += xv.x * W_e1[(k    ) * kH + j];
              s1 += xv.y * W_e1[(k + 1) * kH + j];
              s2 += xv.z * W_e1[(k + 2) * kH + j];
              s3 += xv.w * W_e1[(k + 3) * kH + j];
            }
          }
          const float* mr = mem + (b * kSteps + s) * kI;
          for (int k = 0; k < kI; k += 4) {
            float4 mv = *(const float4*)(mr + k);
            s0 += mv.x * W_e1[(kI + k    ) * kH + j];
            s1 += mv.y * W_e1[(kI + k + 1) * kH + j];
            s2 += mv.z * W_e1[(kI + k + 2) * kH + j];
            s3 += mv.w * W_e1[(kI + k + 3) * kH + j];
          }
          float v = ((s0 + s1) + (s2 + s3)) + b_e1[j];
          av[ii] = v > 0.f ? v : expm1f(v);
        } else {
          int ii = i - nDG1 - nGH - nE1;
          int b = ii / kH, j = ii % kH;
          const float* hr = h + b * kH;  // h == nh of previous decoder step
          float s0 = 0, s1 = 0, s2 = 0, s3 = 0;
          for (int k = 0; k < kH; k += 4) {
            float4 hv = *(const float4*)(hr + k);
            s0 += hv.x * W_f1[(k    ) * kH + j];
            s1 += hv.y * W_f1[(k + 1) * kH + j];
            s2 += hv.z * W_f1[(k + 2) * kH + j];
            s3 += hv.w * W_f1[(k + 3) * kH + j];
          }
          float v = ((s0 + s1) + (s2 + s3)) + b_f1[j];
          o1[ii] = v > 0.f ? v : 0.f;
        }
      }
    }
    gridbar(bar, NB * round); round++;

    // ============ PHASE 2: gi+GRU | f2 (workers), dg2+argmax+scatter ======
    if (bid < NB_M) {
      const int nGRU = rnn  ? kB * kH : 0;   // 8192
      const int nF2  = head ? kB * kC : 0;   // 2048
      const int ntask = nGRU + nF2;
      for (int i = gid; i < ntask; i += NB_M * NTHR) {
        if (i < nGRU) {
          int b = i / kH, j = i % kH;
          const float* ar = av + b * kH;
          const float* w  = W2 + j;
          float r0 = 0, r1 = 0, z0 = 0, z1 = 0, n0 = 0, n1 = 0;
          for (int k = 0; k < kH; k += 2) {
            float2 a2 = *(const float2*)(ar + k);
            const float* wk0 = w + (k    ) * (3 * kH);
            const float* wk1 = w + (k + 1) * (3 * kH);
            r0 += a2.x * wk0[0];      r1 += a2.y * wk1[0];
            z0 += a2.x * wk0[kH];     z1 += a2.y * wk1[kH];
            n0 += a2.x * wk0[2 * kH]; n1 += a2.y * wk1[2 * kH];
          }
          float ir = (r0 + r1) + B2[j];
          float iz = (z0 + z1) + B2[kH + j];
          float in_ = (n0 + n1) + B2[2 * kH + j];
          float hr = gh[b * 3 * kH + j];
          float hz = gh[b * 3 * kH + kH + j];
          float hn = gh[b * 3 * kH + 2 * kH + j];
          float r = 1.f / (1.f + expf(-(ir + hr)));
          float z = 1.f / (1.f + expf(-(iz + hz)));
          float n = tanhf(in_ + r * hn);
          float hold = h[i];
          float nh = (1.f - z) * n + z * hold;
          if (enc) h[i] = (s < lengths[b]) ? nh : hold;  // mask on h only
          else     h[i] = nh;                            // decoder carries nh
        } else {
          int ii = i - nGRU;
          int b = ii / kC, c = ii % kC;
          const float* orow = o1 + b * kH;
          float s0 = 0, s1 = 0, s2 = 0, s3 = 0;
          for (int k = 0; k < kH; k += 4) {
            float4 ov = *(const float4*)(orow + k);
            s0 += ov.x * W_f2[(k    ) * kC + c];
            s1 += ov.y * W_f2[(k + 1) * kC + c];
            s2 += ov.z * W_f2[(k + 2) * kC + c];
            s3 += ov.w * W_f2[(k + 3) * kC + c];
          }
          out[(b * kOut + (s - 1 - kT)) * kC + c] = ((s0 + s1) + (s2 + s3)) + b_f2[c];
        }
      }
    } else if (enc) {
      // dg2 + gumbel argmax + one-hot event scatter (single block)
      if (tid < kD) dec_s[tid] = powf(0.99f, (float)(tid + 1));
      for (int i = tid; i < kB * kD; i += NTHR) {
        int b = i >> 5, j = i & 31;
        const float* lr = l1 + b * kD;
        float sv = b_dg2[j];
        for (int k = 0; k < kD; ++k) sv += lr[k] * W_dg2[k * kD + j];
        lg[b][j] = sv + g[(s * kB + b) * kD + j];
      }
      __syncthreads();
      if (tid < kB) {
        int b = tid;
        float best = lg[b][0]; int bi = 0;
        for (int j = 1; j < kD; ++j) { float v = lg[b][j]; if (v > best) { best = v; bi = j; } }
        sel[b] = bi;
      }
      __syncthreads();
      for (int i = tid; i < kB * kI; i += NTHR) {
        int b = i >> 6, ii = i & 63;
        int d = sel[b];
        int c = s + 1 + d;                    // shift-count at which entry hits slot 0
        int e = -1;
        if (c < kT) e = c;                    // read by encoder step c
        else { int rr = c - kT - 1;           // decoder reads at kT+2k+1
               if (rr >= 0 && (rr & 1) == 0) { int kk = rr >> 1; if (kk < kOut) e = kT + kk; } }
        if (e >= 0)
          mem[(b * kSteps + e) * kI + ii] += x[(b * kT + s) * kI + ii] * dec_s[d];
      }
    }
    gridbar(bar, NB * round); round++;
  }
}

extern "C" void kernel_launch(void* const* d_in, const int* in_sizes, int n_in,
                              void* d_out, int out_size, void* d_ws, size_t ws_size,
                              hipStream_t stream) {
  (void)in_sizes; (void)n_in; (void)out_size; (void)ws_size;
  const float* x      = (const float*)d_in[0];
  const int*   lens   = (const int*)  d_in[1];
  // d_in[2] = out_lengths (fixed 32)
  const float* W_dg1  = (const float*)d_in[3];
  const float* b_dg1  = (const float*)d_in[4];
  const float* W_dg2  = (const float*)d_in[5];
  const float* b_dg2  = (const float*)d_in[6];
  const float* W_e1   = (const float*)d_in[7];
  const float* b_e1   = (const float*)d_in[8];
  const float* W_e2   = (const float*)d_in[9];
  const float* b_e2   = (const float*)d_in[10];
  const float* W_ih   = (const float*)d_in[11];
  const float* b_ih   = (const float*)d_in[12];
  const float* W_hh   = (const float*)d_in[13];
  const float* b_hh   = (const float*)d_in[14];
  const float* W_f1   = (const float*)d_in[15];
  const float* b_f1   = (const float*)d_in[16];
  const float* W_f2   = (const float*)d_in[17];
  const float* b_f2   = (const float*)d_in[18];

  hipMemsetAsync(d_ws, 0, WS_ZERO_BYTES, stream);  // zero barrier + h + mem events
  delay_rnn<<<dim3(NB), dim3(NTHR), 0, stream>>>(
      x, lens, W_dg1, b_dg1, W_dg2, b_dg2, W_e1, b_e1, W_e2, b_e2,
      W_ih, b_ih, W_hh, b_hh, W_f1, b_f1, W_f2, b_f2,
      (float*)d_out, (float*)d_ws);
}

// Round 3
// 4741.310 us; speedup vs baseline: 1.5642x; 1.5642x over previous
//
#include <hip/hip_runtime.h>
#include <math.h>

// ---------------------------------------------------------------------------
// DelayRNN persistent kernel, R3: static column ownership + LDS-resident
// weights. 160 blocks x 256 thr; each block owns fixed 8-col slices and keeps
// its weight slices in LDS across all 161 steps. Only activations (h, av, gh,
// o1, mem_t, x_t) cross global per step. 2 grid barriers per step.
// Phase1 roles: 0..95 gh | 96..127 e1 | 128..131 dg1(enc) / 128..159 f1(head)
// Phase2 roles: 0..31 GRU | 96..103 f2(head) | 128 dg2+argmax+scatter(enc)
// ---------------------------------------------------------------------------

#define kB 32
#define kT 128
#define kI 64
#define kH 256
#define kD 32
#define kC 64
#define kOut 32
#define kSteps (kT + kOut)            // 160
#define NB 160
#define NTHR 256
#define NT_ALL (NB * NTHR)            // 40960

// ws layout, float offsets
#define WS_H    64
#define WS_MEM  (WS_H + kB*kH)                  // h: [B][H]
#define WS_A    (WS_MEM + kB*kSteps*kI)         // mem events: [B][160][I]
#define WS_GH   (WS_A + kB*kH)                  // av: [B][H]
#define WS_L1   (WS_GH + kB*3*kH)               // gh: [B][3H]
#define WS_O1   (WS_L1 + kB*kD)                 // l1: [B][D]
#define WS_W2   (WS_O1 + kB*kH)                 // o1: [B][H]
#define WS_B2   (WS_W2 + kH*3*kH)               // W2 = W_e2@W_ih: [H][3H]
#define WS_G    (WS_B2 + 3*kH)                  // B2: [3H]
#define WS_END  (WS_G + kT*kB*kD)               // g_enc
#define WS_ZERO_BYTES ((size_t)WS_A * sizeof(float))  // zero bar+h+mem

// ---- Threefry-2x32 ----
__device__ __forceinline__ void tf2x32(unsigned k0, unsigned k1,
                                       unsigned x0, unsigned x1,
                                       unsigned& o0, unsigned& o1) {
  unsigned ks2 = k0 ^ k1 ^ 0x1BD11BDAu;
  unsigned v0 = x0 + k0, v1 = x1 + k1;
#define TFR(r) { v0 += v1; v1 = (v1 << (r)) | (v1 >> (32-(r))); v1 ^= v0; }
  TFR(13) TFR(15) TFR(26) TFR(6)   v0 += k1;  v1 += ks2 + 1u;
  TFR(17) TFR(29) TFR(16) TFR(24)  v0 += ks2; v1 += k0  + 2u;
  TFR(13) TFR(15) TFR(26) TFR(6)   v0 += k0;  v1 += k1  + 3u;
  TFR(17) TFR(29) TFR(16) TFR(24)  v0 += k1;  v1 += ks2 + 4u;
  TFR(13) TFR(15) TFR(26) TFR(6)   v0 += ks2; v1 += k0  + 5u;
#undef TFR
  o0 = v0; o1 = v1;
}

__device__ __forceinline__ float bits_to_gumbel(unsigned bits) {
  float f = __uint_as_float((bits >> 9) | 0x3F800000u) - 1.0f;
  float u = f + 1.17549435e-38f;
  return -logf(-logf(u));
}

__device__ __forceinline__ void gridbar(unsigned* bar, unsigned target) {
  __syncthreads();
  if (threadIdx.x == 0) {
    __threadfence();
    __hip_atomic_fetch_add(bar, 1u, __ATOMIC_ACQ_REL, __HIP_MEMORY_SCOPE_AGENT);
    while (__hip_atomic_load(bar, __ATOMIC_RELAXED, __HIP_MEMORY_SCOPE_AGENT) < target)
      __builtin_amdgcn_s_sleep(1);
    __threadfence();
  }
  __syncthreads();
}

__global__ __launch_bounds__(NTHR)
void delay_rnn(const float* __restrict__ x, const int* __restrict__ lengths,
               const float* __restrict__ W_dg1, const float* __restrict__ b_dg1,
               const float* __restrict__ W_dg2, const float* __restrict__ b_dg2,
               const float* __restrict__ W_e1,  const float* __restrict__ b_e1,
               const float* __restrict__ W_e2,  const float* __restrict__ b_e2,
               const float* __restrict__ W_ih,  const float* __restrict__ b_ih,
               const float* __restrict__ W_hh,  const float* __restrict__ b_hh,
               const float* __restrict__ W_f1,  const float* __restrict__ b_f1,
               const float* __restrict__ W_f2,  const float* __restrict__ b_f2,
               float* __restrict__ out, float* __restrict__ ws) {
  const int tid = threadIdx.x;
  const int bid = blockIdx.x;
  const int gid = bid * NTHR + tid;

  unsigned* bar = (unsigned*)ws;
  float* h   = ws + WS_H;
  float* mem = ws + WS_MEM;
  float* av  = ws + WS_A;
  float* gh  = ws + WS_GH;
  float* l1  = ws + WS_L1;
  float* o1  = ws + WS_O1;
  float* W2g = ws + WS_W2;
  float* B2g = ws + WS_B2;
  float* g   = ws + WS_G;

  // LDS carve. Strides padded to %32==4 floats for bank rotation.
  __shared__ float sA[kB * 260];       // stage: h / av / o1 [32][260]
  __shared__ float sB[2 * kB * 68];    // stage: x_t [32][68] + mem_t [32][68]
  __shared__ float w1[8 * 324];        // phase1 wt: GH 8x260 | E1 8x132 | DG1 8x324
  __shared__ float w1f[8 * 260];       // F1 weights
  __shared__ float w2[24 * 260];       // phase2 wt: GRU 24x260 | F2 8x260 | DG2 1024
  __shared__ float bias1[8], bias1f[8], bias2[24], bdg2s[kD], dec_s[kD];
  __shared__ float lg[kB][kD + 1];
  __shared__ int   sel[kB], len_s[kB];

  // ---------------- init: gumbel noise, W2 = W_e2@W_ih, B2 ----------------
  {
    unsigned k0, k1;
    tf2x32(0u, 42u, 0u, 0u, k0, k1);
    const int n = kT * kB * kD;
    for (int i = gid; i < n; i += NT_ALL) {
      unsigned a, b;
      tf2x32(k0, k1, 0u, (unsigned)i, a, b);
      g[i] = bits_to_gumbel(a ^ b);
    }
  }
  for (int idx = gid; idx < kH * 3 * kH; idx += NT_ALL) {
    int k = idx / (3 * kH), n = idx % (3 * kH);
    const float* wr = W_e2 + k * kH;
    float s0 = 0, s1 = 0, s2 = 0, s3 = 0;
    for (int m = 0; m < kH; m += 4) {
      float4 wv = *(const float4*)(wr + m);
      s0 += wv.x * W_ih[(m    ) * 3 * kH + n];
      s1 += wv.y * W_ih[(m + 1) * 3 * kH + n];
      s2 += wv.z * W_ih[(m + 2) * 3 * kH + n];
      s3 += wv.w * W_ih[(m + 3) * 3 * kH + n];
    }
    W2g[idx] = ((s0 + s1) + (s2 + s3));
  }
  for (int n = gid; n < 3 * kH; n += NT_ALL) {
    float s = b_ih[n];
    for (int m = 0; m < kH; ++m) s += b_e2[m] * W_ih[m * 3 * kH + n];
    B2g[n] = s;
  }

  unsigned round = 1;
  gridbar(bar, NB * round); round++;

  // ---------------- stage persistent weight slices into LDS ----------------
  if (bid < 96) {                                      // GH
    const int jb = bid * 8;
    for (int i = tid; i < 2048; i += NTHR) {
      int jj = i >> 8, k = i & 255;
      w1[jj * 260 + k] = W_hh[k * 768 + jb + jj];
    }
    if (tid < 8) bias1[tid] = b_hh[jb + tid];
    if (bid < 32) {                                    // + GRU
      const int jb2 = bid * 8;
      for (int i = tid; i < 6144; i += NTHR) {
        int gg = i >> 11, r = i & 2047, jj = r >> 8, k = r & 255;
        w2[(gg * 8 + jj) * 260 + k] = W2g[k * 768 + gg * kH + jb2 + jj];
      }
      if (tid < 24) { int gg = tid / 8, jj = tid % 8; bias2[tid] = B2g[gg * kH + jb2 + jj]; }
      if (tid < kB) len_s[tid] = lengths[tid];
    }
  } else if (bid < 128) {                              // E1
    const int jb = (bid - 96) * 8;
    for (int i = tid; i < 1024; i += NTHR) {
      int jj = i >> 7, k = i & 127;
      w1[jj * 132 + k] = W_e1[k * kH + jb + jj];
    }
    if (tid < 8) bias1[tid] = b_e1[jb + tid];
    if (bid < 104) {                                   // + F2
      const int cb = (bid - 96) * 8;
      for (int i = tid; i < 2048; i += NTHR) {
        int cc = i >> 8, k = i & 255;
        w2[cc * 260 + k] = W_f2[k * kC + cb + cc];
      }
      if (tid < 8) bias2[tid] = b_f2[cb + tid];
    }
  } else {                                             // DG1 / F1
    const int q = bid - 128, jb = q * 8;
    if (q < 4) {
      for (int i = tid; i < 2560; i += NTHR) {
        int jj = i / 320, k = i % 320;
        w1[jj * 324 + k] = W_dg1[k * kD + jb + jj];
      }
      if (tid < 8) bias1[tid] = b_dg1[jb + tid];
    }
    for (int i = tid; i < 2048; i += NTHR) {
      int jj = i >> 8, k = i & 255;
      w1f[jj * 260 + k] = W_f1[k * kH + jb + jj];
    }
    if (tid < 8) bias1f[tid] = b_f1[jb + tid];
    if (q == 0) {                                      // + DG2/scatter
      for (int i = tid; i < kD * kD; i += NTHR) w2[i] = W_dg2[i];
      if (tid < kD) { bdg2s[tid] = b_dg2[tid]; dec_s[tid] = powf(0.99f, (float)(tid + 1)); }
    }
  }
  __syncthreads();

  const float4* sA4  = (const float4*)sA;
  const float4* sB4  = (const float4*)sB;
  const float4* w14  = (const float4*)w1;
  const float4* w1f4 = (const float4*)w1f;
  const float4* w24  = (const float4*)w2;

  // ---------------- time loop ----------------
  for (int s = 0; s <= kSteps; ++s) {
    const bool enc  = (s < kT);
    const bool rnn  = (s < kSteps);
    const bool head = (s > kT);

    // ================= PHASE 1 =================
    if (bid < 96) {
      if (rnn) {  // gh = h @ W_hh + b_hh
        for (int i = tid; i < kB * kH; i += NTHR)
          sA[(i >> 8) * 260 + (i & 255)] = h[i];
        __syncthreads();
        const int b = tid >> 3, jj = tid & 7;
        float a0 = 0, a1 = 0, a2 = 0, a3 = 0;
        for (int k4 = 0; k4 < 64; ++k4) {
          float4 h4 = sA4[b * 65 + k4];
          float4 w4 = w14[jj * 65 + k4];
          a0 += h4.x * w4.x; a1 += h4.y * w4.y; a2 += h4.z * w4.z; a3 += h4.w * w4.w;
        }
        gh[b * 768 + bid * 8 + jj] = ((a0 + a1) + (a2 + a3)) + bias1[jj];
      }
    } else if (bid < 128) {
      if (rnn) {  // av = elu([x_t, mem_t] @ W_e1 + b_e1)
        for (int i = tid; i < kB * kI; i += NTHR) {
          int b = i >> 6, k = i & 63;
          sB[b * 68 + k] = enc ? x[(b * kT + s) * kI + k] : 0.f;
          sB[2176 + b * 68 + k] = mem[(b * kSteps + s) * kI + k];
        }
        __syncthreads();
        const int b = tid >> 3, jj = tid & 7;
        float a0 = 0, a1 = 0, a2 = 0, a3 = 0;
        for (int k4 = 0; k4 < 16; ++k4) {
          float4 x4 = sB4[b * 17 + k4];
          float4 w4 = w14[jj * 33 + k4];
          a0 += x4.x * w4.x; a1 += x4.y * w4.y; a2 += x4.z * w4.z; a3 += x4.w * w4.w;
        }
        for (int k4 = 0; k4 < 16; ++k4) {
          float4 m4 = sB4[544 + b * 17 + k4];
          float4 w4 = w14[jj * 33 + 16 + k4];
          a0 += m4.x * w4.x; a1 += m4.y * w4.y; a2 += m4.z * w4.z; a3 += m4.w * w4.w;
        }
        float v = ((a0 + a1) + (a2 + a3)) + bias1[jj];
        av[b * kH + (bid - 96) * 8 + jj] = v > 0.f ? v : expm1f(v);
      }
    } else {
      const int q = bid - 128;
      if (enc && q < 4) {  // l1 = elu([x_t, h] @ W_dg1 + b_dg1)
        for (int i = tid; i < kB * kH; i += NTHR)
          sA[(i >> 8) * 260 + (i & 255)] = h[i];
        for (int i = tid; i < kB * kI; i += NTHR) {
          int b = i >> 6, k = i & 63;
          sB[b * 68 + k] = x[(b * kT + s) * kI + k];
        }
        __syncthreads();
        const int b = tid >> 3, jj = tid & 7;
        float a0 = 0, a1 = 0, a2 = 0, a3 = 0;
        for (int k4 = 0; k4 < 16; ++k4) {
          float4 x4 = sB4[b * 17 + k4];
          float4 w4 = w14[jj * 81 + k4];
          a0 += x4.x * w4.x; a1 += x4.y * w4.y; a2 += x4.z * w4.z; a3 += x4.w * w4.w;
        }
        for (int k4 = 0; k4 < 64; ++k4) {
          float4 h4 = sA4[b * 65 + k4];
          float4 w4 = w14[jj * 81 + 16 + k4];
          a0 += h4.x * w4.x; a1 += h4.y * w4.y; a2 += h4.z * w4.z; a3 += h4.w * w4.w;
        }
        float v = ((a0 + a1) + (a2 + a3)) + bias1[jj];
        l1[b * kD + q * 8 + jj] = v > 0.f ? v : expm1f(v);
      } else if (head) {  // o1 = relu(h @ W_f1 + b_f1)
        for (int i = tid; i < kB * kH; i += NTHR)
          sA[(i >> 8) * 260 + (i & 255)] = h[i];
        __syncthreads();
        const int b = tid >> 3, jj = tid & 7;
        float a0 = 0, a1 = 0, a2 = 0, a3 = 0;
        for (int k4 = 0; k4 < 64; ++k4) {
          float4 h4 = sA4[b * 65 + k4];
          float4 w4 = w1f4[jj * 65 + k4];
          a0 += h4.x * w4.x; a1 += h4.y * w4.y; a2 += h4.z * w4.z; a3 += h4.w * w4.w;
        }
        float v = ((a0 + a1) + (a2 + a3)) + bias1f[jj];
        o1[b * kH + q * 8 + jj] = v > 0.f ? v : 0.f;
      }
    }
    gridbar(bar, NB * round); round++;

    // ================= PHASE 2 =================
    if (bid < 32) {
      if (rnn) {  // GRU update
        for (int i = tid; i < kB * kH; i += NTHR)
          sA[(i >> 8) * 260 + (i & 255)] = av[i];
        __syncthreads();
        const int b = tid >> 3, jj = tid & 7;
        const int j = bid * 8 + jj;
        float r0 = 0, r1 = 0, z0 = 0, z1 = 0, n0 = 0, n1 = 0;
        for (int k4 = 0; k4 < 64; ++k4) {
          float4 a4 = sA4[b * 65 + k4];
          float4 wr = w24[(jj     ) * 65 + k4];
          float4 wz = w24[(8  + jj) * 65 + k4];
          float4 wn = w24[(16 + jj) * 65 + k4];
          r0 += a4.x * wr.x + a4.y * wr.y; r1 += a4.z * wr.z + a4.w * wr.w;
          z0 += a4.x * wz.x + a4.y * wz.y; z1 += a4.z * wz.z + a4.w * wz.w;
          n0 += a4.x * wn.x + a4.y * wn.y; n1 += a4.z * wn.z + a4.w * wn.w;
        }
        const float* ghb = gh + b * 768 + j;
        float ir  = (r0 + r1) + bias2[jj]      + ghb[0];
        float iz  = (z0 + z1) + bias2[8 + jj]  + ghb[kH];
        float hn  = ghb[2 * kH];
        float in_ = (n0 + n1) + bias2[16 + jj];
        float r = 1.f / (1.f + expf(-ir));
        float z = 1.f / (1.f + expf(-iz));
        float n = tanhf(in_ + r * hn);
        float hold = h[b * kH + j];
        float nh = (1.f - z) * n + z * hold;
        h[b * kH + j] = enc ? ((s < len_s[b]) ? nh : hold) : nh;
      }
      __syncthreads();  // protect sA reuse before next phase-1 staging
    } else if (bid >= 96 && bid < 104) {
      if (head) {  // out = o1 @ W_f2 + b_f2
        for (int i = tid; i < kB * kH; i += NTHR)
          sA[(i >> 8) * 260 + (i & 255)] = o1[i];
        __syncthreads();
        const int b = tid >> 3, cc = tid & 7;
        float a0 = 0, a1 = 0, a2 = 0, a3 = 0;
        for (int k4 = 0; k4 < 64; ++k4) {
          float4 o4 = sA4[b * 65 + k4];
          float4 w4 = w24[cc * 65 + k4];
          a0 += o4.x * w4.x; a1 += o4.y * w4.y; a2 += o4.z * w4.z; a3 += o4.w * w4.w;
        }
        out[(b * kOut + (s - 1 - kT)) * kC + (bid - 96) * 8 + cc] =
            ((a0 + a1) + (a2 + a3)) + bias2[cc];
      }
      __syncthreads();
    } else if (bid == 128) {
      if (enc) {  // dg2 + gumbel argmax + event scatter
        for (int i = tid; i < kB * kD; i += NTHR) {
          int b = i >> 5, j = i & 31;
          const float* lr = l1 + b * kD;
          float sv = bdg2s[j];
          for (int k = 0; k < kD; ++k) sv += lr[k] * w2[k * kD + j];
          lg[b][j] = sv + g[(s * kB + b) * kD + j];
        }
        __syncthreads();
        if (tid < kB) {
          float best = lg[tid][0]; int bi = 0;
          for (int j = 1; j < kD; ++j) { float v = lg[tid][j]; if (v > best) { best = v; bi = j; } }
          sel[tid] = bi;
        }
        __syncthreads();
        for (int i = tid; i < kB * kI; i += NTHR) {
          int b = i >> 6, ii = i & 63;
          int d = sel[b];
          int c = s + 1 + d;
          int e = -1;
          if (c < kT) e = c;
          else { int rr = c - kT - 1;
                 if (rr >= 0 && (rr & 1) == 0) { int kk = rr >> 1; if (kk < kOut) e = kT + kk; } }
          if (e >= 0)
            mem[(b * kSteps + e) * kI + ii] += x[(b * kT + s) * kI + ii] * dec_s[d];
        }
      }
    }
    gridbar(bar, NB * round); round++;
  }
}

extern "C" void kernel_launch(void* const* d_in, const int* in_sizes, int n_in,
                              void* d_out, int out_size, void* d_ws, size_t ws_size,
                              hipStream_t stream) {
  (void)in_sizes; (void)n_in; (void)out_size; (void)ws_size;
  const float* x      = (const float*)d_in[0];
  const int*   lens   = (const int*)  d_in[1];
  const float* W_dg1  = (const float*)d_in[3];
  const float* b_dg1  = (const float*)d_in[4];
  const float* W_dg2  = (const float*)d_in[5];
  const float* b_dg2  = (const float*)d_in[6];
  const float* W_e1   = (const float*)d_in[7];
  const float* b_e1   = (const float*)d_in[8];
  const float* W_e2   = (const float*)d_in[9];
  const float* b_e2   = (const float*)d_in[10];
  const float* W_ih   = (const float*)d_in[11];
  const float* b_ih   = (const float*)d_in[12];
  const float* W_hh   = (const float*)d_in[13];
  const float* b_hh   = (const float*)d_in[14];
  const float* W_f1   = (const float*)d_in[15];
  const float* b_f1   = (const float*)d_in[16];
  const float* W_f2   = (const float*)d_in[17];
  const float* b_f2   = (const float*)d_in[18];

  hipMemsetAsync(d_ws, 0, WS_ZERO_BYTES, stream);
  delay_rnn<<<dim3(NB), dim3(NTHR), 0, stream>>>(
      x, lens, W_dg1, b_dg1, W_dg2, b_dg2, W_e1, b_e1, W_e2, b_e2,
      W_ih, b_ih, W_hh, b_hh, W_f1, b_f1, W_f2, b_f2,
      (float*)d_out, (float*)d_ws);
}